// Round 2
// 2232.676 us; speedup vs baseline: 1.0481x; 1.0481x over previous
//
#include <hip/hip_runtime.h>
#include <hip/hip_fp16.h>
#include <math.h>

// ---------------------------------------------------------------------------
// CGNR solver: v = argmin ||H v - x|| via CG on (H^T H) v = H^T x, 32 iters,
// then reconstruction + time/frequency metrics.  N = 8192.
//
// Round 7 (resubmit; round-1 bench was an infra timeout): FUSED
// normal-equations pass.  s = H^T (H p) is computed in ONE kernel that reads
// each row of H for the dot (t_i = H[i,:].p) and immediately re-reads it
// (L3-hot) for the axpy (s_part += t_i * H[i,:]).  H is stored ONCE as fp16
// (128 MiB -> fits Infinity Cache), no transposed copy, no LDS-transpose
// convert.  HBM traffic per iteration: 134 MB (was 268 MB).  Per-block
// partial s vectors (512 x 8192 fp32 = 16 MB) are combined in a small
// reduce+update kernel that also applies alpha and computes the new rs.
//
// sc[] slots: RS[it]=sc[it] (0..32), TT[it]=sc[40+it], metrics msc=sc+80.
// ---------------------------------------------------------------------------

#define NN 8192
#define NITER 32
#define EPSF 1e-20f

typedef unsigned short ushort_t;

__device__ __forceinline__ float wave_red(float v) {
    #pragma unroll
    for (int off = 32; off; off >>= 1) v += __shfl_xor(v, off, 64);
    return v;
}

__device__ __forceinline__ void wred_atomic(float v, float* addr) {
    v = wave_red(v);
    if ((threadIdx.x & 63) == 0) atomicAdd(addr, v);
}

__device__ __forceinline__ void unpack8(uint4 u, float* f) {
    union { unsigned int i; __half2 h; } c0, c1, c2, c3;
    c0.i = u.x; c1.i = u.y; c2.i = u.z; c3.i = u.w;
    float2 f0 = __half22float2(c0.h);
    float2 f1 = __half22float2(c1.h);
    float2 f2 = __half22float2(c2.h);
    float2 f3 = __half22float2(c3.h);
    f[0] = f0.x; f[1] = f0.y; f[2] = f1.x; f[3] = f1.y;
    f[4] = f2.x; f[5] = f2.y; f[6] = f3.x; f[7] = f3.y;
}

// --- one-time: H fp32 -> fp16 straight stream copy (no transpose) ----------
__global__ __launch_bounds__(256) void h_convert(const float4* __restrict__ Hf,
                                                 uint4* __restrict__ Hh) {
    const size_t i = (size_t)blockIdx.x * 256 + threadIdx.x;
    float4 a = Hf[2 * i], b = Hf[2 * i + 1];
    __half2 h0 = __floats2half2_rn(a.x, a.y);
    __half2 h1 = __floats2half2_rn(a.z, a.w);
    __half2 h2 = __floats2half2_rn(b.x, b.y);
    __half2 h3 = __floats2half2_rn(b.z, b.w);
    uint4 o;
    o.x = *(unsigned int*)&h0; o.y = *(unsigned int*)&h1;
    o.z = *(unsigned int*)&h2; o.w = *(unsigned int*)&h3;
    Hh[i] = o;
}

// --- load 16 columns of one H row into fp32 regs ---------------------------
template <int HM>
__device__ __forceinline__ void row_load(const void* __restrict__ Hp, int row,
                                         int tid, float* h) {
    if (HM) {
        const uint4* hp = (const uint4*)((const ushort_t*)Hp + (size_t)row * NN)
                        + tid * 2;
        uint4 u0 = hp[0], u1 = hp[1];
        unpack8(u0, h);
        unpack8(u1, h + 8);
    } else {
        const float4* hp = (const float4*)((const float*)Hp + (size_t)row * NN)
                         + tid * 4;
        #pragma unroll
        for (int q = 0; q < 4; ++q) {
            float4 f = hp[q];
            h[4*q+0] = f.x; h[4*q+1] = f.y; h[4*q+2] = f.z; h[4*q+3] = f.w;
        }
    }
}

// --- fused normal-equations pass -------------------------------------------
// mode 1:  pn = r + beta*p ; t = H pn ; TT += ||t||^2 ;
//          spart[blk] = sum_{rows of blk} t_i * H[i,:] ; block0 stores pn.
// mode 0:  spart[blk] = sum_{rows of blk} x_i * H[i,:]   (b = H^T x init)
// grid nb blocks x 512 thr; thread owns 16 columns; rpb = NN/nb rows/block.
template <int HM>
__global__ __launch_bounds__(512, 4) void fused_pass(
        const void* __restrict__ Hp,
        const float* __restrict__ rr,
        const float* __restrict__ pp,
        const float* __restrict__ x,
        const float* __restrict__ sc,
        int bnum, int bden, int first, int mode, int rpb,
        float* __restrict__ tout,
        float* __restrict__ ttout,
        float* __restrict__ pout,
        float* __restrict__ spart) {
    const int tid  = threadIdx.x;
    const int wave = tid >> 6;
    const int lane = tid & 63;
    __shared__ float part[8][16];
    __shared__ float tl[16];

    float pn[16], sacc[16];
    #pragma unroll
    for (int k = 0; k < 16; ++k) sacc[k] = 0.f;

    if (mode == 1) {
        const float beta = first ? 0.f : sc[bnum] / (sc[bden] + EPSF);
        const float4* r4 = (const float4*)rr + tid * 4;
        const float4* p4 = (const float4*)pp + tid * 4;
        #pragma unroll
        for (int q = 0; q < 4; ++q) {
            float4 a = r4[q], b = p4[q];
            pn[4*q+0] = a.x + beta * b.x; pn[4*q+1] = a.y + beta * b.y;
            pn[4*q+2] = a.z + beta * b.z; pn[4*q+3] = a.w + beta * b.w;
        }
        if (blockIdx.x == 0) {
            float4* o4 = (float4*)pout + tid * 4;
            #pragma unroll
            for (int q = 0; q < 4; ++q) {
                float4 w;
                w.x = pn[4*q+0]; w.y = pn[4*q+1];
                w.z = pn[4*q+2]; w.w = pn[4*q+3];
                o4[q] = w;
            }
        }
    }

    const int rbase = blockIdx.x * rpb;

    for (int ch = 0; ch < rpb; ch += 16) {
        if (mode == 1) {
            // phase 1: row dots t_i = H[i,:].pn
            #pragma unroll 2
            for (int i = 0; i < 16; ++i) {
                const int row = rbase + ch + i;
                float h[16];
                row_load<HM>(Hp, row, tid, h);
                float d = 0.f;
                #pragma unroll
                for (int k = 0; k < 16; ++k) d += h[k] * pn[k];
                d = wave_red(d);
                if (lane == 0) part[wave][i] = d;
            }
            __syncthreads();
            if (wave == 0) {
                float tv = 0.f;
                if (lane < 16) {
                    #pragma unroll
                    for (int w = 0; w < 8; ++w) tv += part[w][lane];
                    tl[lane] = tv;
                    tout[rbase + ch + lane] = tv;
                }
                const float sq = wave_red(tv * tv);
                if (lane == 0) atomicAdd(ttout, sq);
            }
            __syncthreads();
        }
        // phase 2: axpy  sacc += t_i * H[i,:]   (rows re-read -> L3 hit)
        #pragma unroll 2
        for (int i = 0; i < 16; ++i) {
            const int row = rbase + ch + i;
            float h[16];
            row_load<HM>(Hp, row, tid, h);
            const float ti = (mode == 0) ? x[row] : tl[i];
            #pragma unroll
            for (int k = 0; k < 16; ++k) sacc[k] += ti * h[k];
        }
        // next chunk's post-phase-1 barrier orders tl/part reuse; no extra
        // barrier needed here.
    }

    float4* sp = (float4*)(spart + (size_t)blockIdx.x * NN) + tid * 4;
    #pragma unroll
    for (int q = 0; q < 4; ++q) {
        float4 w;
        w.x = sacc[4*q+0]; w.y = sacc[4*q+1];
        w.z = sacc[4*q+2]; w.w = sacc[4*q+3];
        sp[q] = w;
    }
}

// --- combine spart column-wise -> s ; apply CG update ----------------------
// mode 0: r = s, RS += s^2
// mode 1: alpha=RS/TT; v += alpha pn; qh += alpha t; r -= alpha s; RS' += r^2
// grid 32 x 1024; col = blk*256 + (tid&255); bq = tid>>8 splits the b-range.
__global__ __launch_bounds__(1024) void reduce_update(
        const float* __restrict__ spart, int nb,
        const float* __restrict__ t,
        const float* __restrict__ pn,
        float* __restrict__ r,
        float* __restrict__ v,
        float* __restrict__ qh,
        const float* __restrict__ sc,
        int anum, int aden,
        float* __restrict__ rsout,
        int mode) {
    const int col = blockIdx.x * 256 + (threadIdx.x & 255);
    const int bq  = threadIdx.x >> 8;
    float s = 0.f;
    #pragma unroll 8
    for (int b = bq; b < nb; b += 4)
        s += spart[(size_t)b * NN + col];
    __shared__ float red[4][256];
    red[bq][threadIdx.x & 255] = s;
    __syncthreads();
    if (bq == 0) {
        s = red[0][threadIdx.x] + red[1][threadIdx.x]
          + red[2][threadIdx.x] + red[3][threadIdx.x];
        float rn;
        if (mode == 0) {
            rn = s;
        } else {
            const float alpha = sc[anum] / (sc[aden] + EPSF);
            v[col]  += alpha * pn[col];
            qh[col] += alpha * t[col];
            rn = r[col] - alpha * s;
        }
        r[col] = rn;
        wred_atomic(rn * rn, rsout);
    }
}

// --- prep: zero v, qh and scalar slots ------------------------------------
__global__ __launch_bounds__(256) void prep(float* v, float* qh, float* sc) {
    const int i = blockIdx.x * 256 + threadIdx.x;
    v[i] = 0.f; qh[i] = 0.f;
    if (i < 128) sc[i] = 0.f;
}

// --- time-domain metrics + difference signals + v output ------------------
__global__ __launch_bounds__(256) void metrics1(const float* __restrict__ qh,
                                                const float* __restrict__ v,
                                                const float* __restrict__ x,
                                                const float* __restrict__ vt,
                                                const float* __restrict__ qt,
                                                float* __restrict__ dv,
                                                float* __restrict__ dq,
                                                float* msc,
                                                float* __restrict__ out) {
    const int i = blockIdx.x * 256 + threadIdx.x;
    const float qhv = qh[i], vv = v[i];
    const float xv = x[i], vtv = vt[i], qtv = qt[i];
    const float dqi = qhv - qtv, dvi = vv - vtv;
    dq[i] = dqi; dv[i] = dvi;
    out[i] = vv;
    const float sg = (i & 1) ? -1.f : 1.f;
    const float rx = qhv - xv;
    wred_atomic(rx * rx,    &msc[3]);
    wred_atomic(fabsf(dqi), &msc[4]);
    wred_atomic(dqi * dqi,  &msc[5]);
    wred_atomic(qtv * qtv,  &msc[6]);
    wred_atomic(fabsf(dvi), &msc[7]);
    wred_atomic(dvi * dvi,  &msc[8]);
    wred_atomic(vtv * vtv,  &msc[9]);
    wred_atomic(dqi,        &msc[10]);
    wred_atomic(sg * dqi,   &msc[11]);
    wred_atomic(qtv,        &msc[12]);
    wred_atomic(sg * qtv,   &msc[13]);
    wred_atomic(dvi,        &msc[14]);
    wred_atomic(sg * dvi,   &msc[15]);
    wred_atomic(vtv,        &msc[16]);
    wred_atomic(sg * vtv,   &msc[17]);
}

// --- direct rDFT magnitudes: one wave per bin k (0..4096) ------------------
__global__ __launch_bounds__(256) void dftmag(const float* __restrict__ dv,
                                              const float* __restrict__ dq,
                                              float* msc) {
    const int wave = threadIdx.x >> 6;
    const int lane = threadIdx.x & 63;
    const int k = blockIdx.x * 4 + wave;
    const float* sig = blockIdx.y ? dq : dv;
    float re = 0.f, im = 0.f;
    if (k <= 4096) {
        const float C = 2.0f * 3.14159265358979323846f / 8192.0f;
        int phase = (k * lane) & 8191;
        const int step = (k << 6) & 8191;
        for (int j = 0; j < 128; ++j) {
            const float s = sig[j * 64 + lane];
            float sn, cs;
            sincosf(C * (float)phase, &sn, &cs);
            re += s * cs; im += s * sn;
            phase = (phase + step) & 8191;
        }
    }
    re = wave_red(re); im = wave_red(im);
    __shared__ float mg[4];
    if (lane == 0) mg[wave] = (k <= 4096) ? sqrtf(re * re + im * im) : 0.f;
    __syncthreads();
    if (threadIdx.x == 0)
        atomicAdd(&msc[18 + blockIdx.y], mg[0] + mg[1] + mg[2] + mg[3]);
}

// --- finalize 11 scalar outputs -------------------------------------------
__global__ void finalize(const float* __restrict__ msc,
                         float* __restrict__ out) {
    if (threadIdx.x == 0 && blockIdx.x == 0) {
        const float Nf = 8192.0f;
        const float Sdq = 0.5f * (Nf * msc[5] + msc[10]*msc[10] + msc[11]*msc[11]);
        const float Sqt = 0.5f * (Nf * msc[6] + msc[12]*msc[12] + msc[13]*msc[13]);
        const float Sdv = 0.5f * (Nf * msc[8] + msc[14]*msc[14] + msc[15]*msc[15]);
        const float Svt = 0.5f * (Nf * msc[9] + msc[16]*msc[16] + msc[17]*msc[17]);
        out[8192 + 0]  = sqrtf(msc[3]);
        out[8192 + 1]  = msc[4] / Nf;
        out[8192 + 2]  = msc[5] / (msc[6] + EPSF);
        out[8192 + 3]  = msc[7] / Nf;
        out[8192 + 4]  = msc[8] / (msc[9] + EPSF);
        out[8192 + 5]  = msc[5] / Nf;
        out[8192 + 6]  = msc[8] / Nf;
        out[8192 + 7]  = msc[19] / 4097.0f;
        out[8192 + 8]  = Sdq / (Sqt + EPSF);
        out[8192 + 9]  = msc[18] / 4097.0f;
        out[8192 + 10] = Sdv / (Svt + EPSF);
    }
}

// ---------------------------------------------------------------------------
extern "C" void kernel_launch(void* const* d_in, const int* in_sizes, int n_in,
                              void* d_out, int out_size, void* d_ws, size_t ws_size,
                              hipStream_t stream) {
    const float* x  = (const float*)d_in[1];
    const float* H  = (const float*)d_in[2];
    const float* vt = (const float*)d_in[3];
    const float* qt = (const float*)d_in[4];

    const size_t HH_BYTES  = (size_t)NN * NN * 2;   // 134,217,728 (fp16 H)
    const size_t VEC_BYTES = 80000ull * 4;

    int nb = 512;                                    // row-blocks in fused pass
    const bool fp16ok =
        ws_size >= HH_BYTES + (size_t)512 * NN * 4 + VEC_BYTES;

    ushort_t* Hh = (ushort_t*)d_ws;
    float* spart;
    float* vecs;
    if (fp16ok) {
        spart = (float*)((char*)d_ws + HH_BYTES);
        vecs  = spart + (size_t)512 * NN;
    } else {
        // fp32-direct fallback: only spart + vectors in ws
        while (nb > 64 && ws_size < (size_t)nb * NN * 4 + VEC_BYTES) nb >>= 1;
        spart = (float*)d_ws;
        vecs  = spart + (size_t)nb * NN;
    }
    const int rpb = NN / nb;

    float* v   = vecs;
    float* r   = vecs + 8192;
    float* pA  = vecs + 16384;
    float* pB  = vecs + 24576;
    float* t   = vecs + 32768;
    float* qh  = vecs + 40960;
    float* dv  = vecs + 49152;
    float* dq  = vecs + 57344;
    float* sc  = vecs + 65536;
    float* msc = sc + 80;
    float* out = (float*)d_out;
    float* pbuf[2] = { pA, pB };

    if (fp16ok)
        h_convert<<<32768, 256, 0, stream>>>((const float4*)H, (uint4*)Hh);
    prep<<<32, 256, 0, stream>>>(v, qh, sc);

    const void* Hp = fp16ok ? (const void*)Hh : (const void*)H;

    // init: b = H^T x  ->  r = b, RS[0] = b.b
    if (fp16ok)
        fused_pass<1><<<nb, 512, 0, stream>>>(Hp, r, r, x, sc, 0, 0, 1, 0, rpb,
                                              t, &sc[79], pA, spart);
    else
        fused_pass<0><<<nb, 512, 0, stream>>>(Hp, r, r, x, sc, 0, 0, 1, 0, rpb,
                                              t, &sc[79], pA, spart);
    reduce_update<<<32, 1024, 0, stream>>>(spart, nb, t, pA, r, v, qh, sc,
                                           0, 0, &sc[0], 0);

    for (int it = 0; it < NITER; ++it) {
        const float* pread = (it == 0) ? r : pbuf[(it - 1) & 1];
        float* pwrite = pbuf[it & 1];
        if (fp16ok)
            fused_pass<1><<<nb, 512, 0, stream>>>(Hp, r, pread, x, sc,
                                                  it, it - 1, (it == 0) ? 1 : 0,
                                                  1, rpb, t, &sc[40 + it],
                                                  pwrite, spart);
        else
            fused_pass<0><<<nb, 512, 0, stream>>>(Hp, r, pread, x, sc,
                                                  it, it - 1, (it == 0) ? 1 : 0,
                                                  1, rpb, t, &sc[40 + it],
                                                  pwrite, spart);
        reduce_update<<<32, 1024, 0, stream>>>(spart, nb, t, pwrite, r, v, qh,
                                               sc, it, 40 + it, &sc[it + 1], 1);
    }

    metrics1<<<32, 256, 0, stream>>>(qh, v, x, vt, qt, dv, dq, msc, out);
    dim3 g(1025, 2);
    dftmag<<<g, 256, 0, stream>>>(dv, dq, msc);
    finalize<<<1, 64, 0, stream>>>(sc + 80, out);
}

// Round 3
// 1751.860 us; speedup vs baseline: 1.3358x; 1.2745x over previous
//
#include <hip/hip_runtime.h>
#include <hip/hip_fp16.h>
#include <math.h>

// ---------------------------------------------------------------------------
// CGNR solver: v = argmin ||H v - x|| via CG on (H^T H) v = H^T x, 32 iters,
// then reconstruction + time/frequency metrics.  N = 8192.
//
// Round 8: register-resident fused pass.  Round-7 profiling showed the
// phase-2 re-read of H missed L3 (aggregate in-flight set across 512 blocks
// ~= 256 MB = L3 capacity), so each iteration paid ~268 MB of HBM.  Fix:
// reduce the row dot block-wide EVERY 2 ROWS and keep the packed fp16 row
// fragment in registers across the reduction -> the axpy s += t_i*H[i,:]
// reads H from REGISTERS.  H is read exactly once per iteration (134 MB),
// no cache dependence.  1 barrier per 2-row step via double-buffered LDS
// partials; next-pair prefetch keeps loads in flight across the barrier.
// The fp32->fp16 convert is folded into the init pass (b = H^T x).
//
// sc[] slots: RS[it]=sc[it] (0..32), TT[it]=sc[40+it], metrics msc=sc+80.
// ---------------------------------------------------------------------------

#define NN 8192
#define NITER 32
#define EPSF 1e-20f

typedef unsigned short ushort_t;

__device__ __forceinline__ float wave_red(float v) {
    #pragma unroll
    for (int off = 32; off; off >>= 1) v += __shfl_xor(v, off, 64);
    return v;
}

__device__ __forceinline__ void wred_atomic(float v, float* addr) {
    v = wave_red(v);
    if ((threadIdx.x & 63) == 0) atomicAdd(addr, v);
}

__device__ __forceinline__ void unpack8(uint4 u, float* f) {
    union { unsigned int i; __half2 h; } c0, c1, c2, c3;
    c0.i = u.x; c1.i = u.y; c2.i = u.z; c3.i = u.w;
    float2 f0 = __half22float2(c0.h);
    float2 f1 = __half22float2(c1.h);
    float2 f2 = __half22float2(c2.h);
    float2 f3 = __half22float2(c3.h);
    f[0] = f0.x; f[1] = f0.y; f[2] = f1.x; f[3] = f1.y;
    f[4] = f2.x; f[5] = f2.y; f[6] = f3.x; f[7] = f3.y;
}

// --- packed row fragment (one thread's 16 columns of one H row) ------------
template <int HM> struct RowT;
template <> struct RowT<1> { uint4 a, b; };          // 16 fp16
template <> struct RowT<0> { float f[16]; };         // 16 fp32

__device__ __forceinline__ void load_row(const void* Hp, int row, int tid,
                                         RowT<1>& c) {
    const uint4* hp = (const uint4*)((const ushort_t*)Hp + (size_t)row * NN)
                    + tid * 2;
    c.a = hp[0]; c.b = hp[1];
}
__device__ __forceinline__ void load_row(const void* Hp, int row, int tid,
                                         RowT<0>& c) {
    const float4* hp = (const float4*)((const float*)Hp + (size_t)row * NN)
                     + tid * 4;
    #pragma unroll
    for (int q = 0; q < 4; ++q) {
        float4 v = hp[q];
        c.f[4*q+0] = v.x; c.f[4*q+1] = v.y; c.f[4*q+2] = v.z; c.f[4*q+3] = v.w;
    }
}
__device__ __forceinline__ void unpack_row(const RowT<1>& c, float* f) {
    unpack8(c.a, f); unpack8(c.b, f + 8);
}
__device__ __forceinline__ void unpack_row(const RowT<0>& c, float* f) {
    #pragma unroll
    for (int k = 0; k < 16; ++k) f[k] = c.f[k];
}

// --- fused normal-equations pass -------------------------------------------
// mode 1:  pn = r + beta*p ; t = H pn ; TT += ||t||^2 ;
//          spart[blk] = sum_{rows of blk} t_i * H[i,:] ; block0 stores pn.
//          H rows stay in REGISTERS between the dot and the axpy.
// mode 0:  spart[blk] = sum_{rows of blk} x_i * H[i,:]   (b = H^T x init);
//          CONV=1 additionally writes the fp16 copy of H.
// grid nb x 512 thr; thread owns 16 columns; rpb = NN/nb rows/block (even).
template <int HM, int CONV>
__global__ __launch_bounds__(512, 4) void fused_pass(
        const void* __restrict__ Hp,
        ushort_t* __restrict__ Hh_out,
        const float* __restrict__ rr,
        const float* __restrict__ pp,
        const float* __restrict__ x,
        const float* __restrict__ sc,
        int bnum, int bden, int first, int mode, int rpb,
        float* __restrict__ tout,
        float* __restrict__ ttout,
        float* __restrict__ pout,
        float* __restrict__ spart) {
    const int tid  = threadIdx.x;
    const int wave = tid >> 6;
    const int lane = tid & 63;
    __shared__ float part[2][8][2];

    float sacc[16];
    #pragma unroll
    for (int k = 0; k < 16; ++k) sacc[k] = 0.f;

    const int rbase = blockIdx.x * rpb;

    if (mode == 0) {
        // ---- init: b = H^T x (single sweep; optional fp32->fp16 convert) --
        #pragma unroll 2
        for (int i = 0; i < rpb; ++i) {
            const int row = rbase + i;
            RowT<HM> c;
            load_row(Hp, row, tid, c);
            float f[16];
            unpack_row(c, f);
            if (CONV) {
                uint4 pa, pb;
                __half2 h0 = __floats2half2_rn(f[0],  f[1]);
                __half2 h1 = __floats2half2_rn(f[2],  f[3]);
                __half2 h2 = __floats2half2_rn(f[4],  f[5]);
                __half2 h3 = __floats2half2_rn(f[6],  f[7]);
                __half2 h4 = __floats2half2_rn(f[8],  f[9]);
                __half2 h5 = __floats2half2_rn(f[10], f[11]);
                __half2 h6 = __floats2half2_rn(f[12], f[13]);
                __half2 h7 = __floats2half2_rn(f[14], f[15]);
                pa.x = *(unsigned int*)&h0; pa.y = *(unsigned int*)&h1;
                pa.z = *(unsigned int*)&h2; pa.w = *(unsigned int*)&h3;
                pb.x = *(unsigned int*)&h4; pb.y = *(unsigned int*)&h5;
                pb.z = *(unsigned int*)&h6; pb.w = *(unsigned int*)&h7;
                uint4* dst = (uint4*)(Hh_out + (size_t)row * NN) + tid * 2;
                dst[0] = pa; dst[1] = pb;
            }
            const float xv = x[row];
            #pragma unroll
            for (int k = 0; k < 16; ++k) sacc[k] += xv * f[k];
        }
    } else {
        // ---- CG iteration: pn build, then 2-rows-per-step pipeline --------
        float pn[16];
        const float beta = first ? 0.f : sc[bnum] / (sc[bden] + EPSF);
        {
            const float4* r4 = (const float4*)rr + tid * 4;
            const float4* p4 = (const float4*)pp + tid * 4;
            #pragma unroll
            for (int q = 0; q < 4; ++q) {
                float4 a = r4[q], b = p4[q];
                pn[4*q+0] = a.x + beta * b.x; pn[4*q+1] = a.y + beta * b.y;
                pn[4*q+2] = a.z + beta * b.z; pn[4*q+3] = a.w + beta * b.w;
            }
            if (blockIdx.x == 0) {
                float4* o4 = (float4*)pout + tid * 4;
                #pragma unroll
                for (int q = 0; q < 4; ++q) {
                    float4 w;
                    w.x = pn[4*q+0]; w.y = pn[4*q+1];
                    w.z = pn[4*q+2]; w.w = pn[4*q+3];
                    o4[q] = w;
                }
            }
        }

        const int nstep = rpb >> 1;          // 2 rows per step
        float ttacc = 0.f;
        RowT<HM> c0, c1, n0, n1;
        load_row(Hp, rbase + 0, tid, c0);
        load_row(Hp, rbase + 1, tid, c1);

        for (int k = 0; k < nstep; ++k) {
            if (k + 1 < nstep) {              // prefetch next pair
                load_row(Hp, rbase + 2 * (k + 1) + 0, tid, n0);
                load_row(Hp, rbase + 2 * (k + 1) + 1, tid, n1);
            }
            float f0[16], f1[16];
            unpack_row(c0, f0);
            unpack_row(c1, f1);
            float dA = 0.f, dB = 0.f;
            #pragma unroll
            for (int j = 0; j < 16; ++j) { dA += f0[j] * pn[j]; dB += f1[j] * pn[j]; }
            dA = wave_red(dA); dB = wave_red(dB);
            const int kb = k & 1;
            if (lane == 0) { part[kb][wave][0] = dA; part[kb][wave][1] = dB; }
            __syncthreads();                  // single barrier per step
            float tvA = 0.f, tvB = 0.f;
            #pragma unroll
            for (int w = 0; w < 8; ++w) {     // broadcast LDS reads
                tvA += part[kb][w][0];
                tvB += part[kb][w][1];
            }
            if (tid == 0) {
                tout[rbase + 2 * k + 0] = tvA;
                tout[rbase + 2 * k + 1] = tvB;
                ttacc += tvA * tvA + tvB * tvB;
            }
            #pragma unroll
            for (int j = 0; j < 16; ++j) sacc[j] += tvA * f0[j] + tvB * f1[j];
            c0 = n0; c1 = n1;                 // register renames
        }
        if (tid == 0) atomicAdd(ttout, ttacc);
    }

    float4* sp = (float4*)(spart + (size_t)blockIdx.x * NN) + tid * 4;
    #pragma unroll
    for (int q = 0; q < 4; ++q) {
        float4 w;
        w.x = sacc[4*q+0]; w.y = sacc[4*q+1];
        w.z = sacc[4*q+2]; w.w = sacc[4*q+3];
        sp[q] = w;
    }
}

// --- combine spart column-wise -> s ; apply CG update ----------------------
// mode 0: r = s, RS += s^2
// mode 1: alpha=RS/TT; v += alpha pn; qh += alpha t; r -= alpha s; RS' += r^2
__global__ __launch_bounds__(1024) void reduce_update(
        const float* __restrict__ spart, int nb,
        const float* __restrict__ t,
        const float* __restrict__ pn,
        float* __restrict__ r,
        float* __restrict__ v,
        float* __restrict__ qh,
        const float* __restrict__ sc,
        int anum, int aden,
        float* __restrict__ rsout,
        int mode) {
    const int col = blockIdx.x * 256 + (threadIdx.x & 255);
    const int bq  = threadIdx.x >> 8;
    float s = 0.f;
    #pragma unroll 8
    for (int b = bq; b < nb; b += 4)
        s += spart[(size_t)b * NN + col];
    __shared__ float red[4][256];
    red[bq][threadIdx.x & 255] = s;
    __syncthreads();
    if (bq == 0) {
        s = red[0][threadIdx.x] + red[1][threadIdx.x]
          + red[2][threadIdx.x] + red[3][threadIdx.x];
        float rn;
        if (mode == 0) {
            rn = s;
        } else {
            const float alpha = sc[anum] / (sc[aden] + EPSF);
            v[col]  += alpha * pn[col];
            qh[col] += alpha * t[col];
            rn = r[col] - alpha * s;
        }
        r[col] = rn;
        wred_atomic(rn * rn, rsout);
    }
}

// --- prep: zero v, qh and scalar slots ------------------------------------
__global__ __launch_bounds__(256) void prep(float* v, float* qh, float* sc) {
    const int i = blockIdx.x * 256 + threadIdx.x;
    v[i] = 0.f; qh[i] = 0.f;
    if (i < 128) sc[i] = 0.f;
}

// --- time-domain metrics + difference signals + v output ------------------
__global__ __launch_bounds__(256) void metrics1(const float* __restrict__ qh,
                                                const float* __restrict__ v,
                                                const float* __restrict__ x,
                                                const float* __restrict__ vt,
                                                const float* __restrict__ qt,
                                                float* __restrict__ dv,
                                                float* __restrict__ dq,
                                                float* msc,
                                                float* __restrict__ out) {
    const int i = blockIdx.x * 256 + threadIdx.x;
    const float qhv = qh[i], vv = v[i];
    const float xv = x[i], vtv = vt[i], qtv = qt[i];
    const float dqi = qhv - qtv, dvi = vv - vtv;
    dq[i] = dqi; dv[i] = dvi;
    out[i] = vv;
    const float sg = (i & 1) ? -1.f : 1.f;
    const float rx = qhv - xv;
    wred_atomic(rx * rx,    &msc[3]);
    wred_atomic(fabsf(dqi), &msc[4]);
    wred_atomic(dqi * dqi,  &msc[5]);
    wred_atomic(qtv * qtv,  &msc[6]);
    wred_atomic(fabsf(dvi), &msc[7]);
    wred_atomic(dvi * dvi,  &msc[8]);
    wred_atomic(vtv * vtv,  &msc[9]);
    wred_atomic(dqi,        &msc[10]);
    wred_atomic(sg * dqi,   &msc[11]);
    wred_atomic(qtv,        &msc[12]);
    wred_atomic(sg * qtv,   &msc[13]);
    wred_atomic(dvi,        &msc[14]);
    wred_atomic(sg * dvi,   &msc[15]);
    wred_atomic(vtv,        &msc[16]);
    wred_atomic(sg * vtv,   &msc[17]);
}

// --- direct rDFT magnitudes: one wave per bin k (0..4096) ------------------
__global__ __launch_bounds__(256) void dftmag(const float* __restrict__ dv,
                                              const float* __restrict__ dq,
                                              float* msc) {
    const int wave = threadIdx.x >> 6;
    const int lane = threadIdx.x & 63;
    const int k = blockIdx.x * 4 + wave;
    const float* sig = blockIdx.y ? dq : dv;
    float re = 0.f, im = 0.f;
    if (k <= 4096) {
        const float C = 2.0f * 3.14159265358979323846f / 8192.0f;
        int phase = (k * lane) & 8191;
        const int step = (k << 6) & 8191;
        for (int j = 0; j < 128; ++j) {
            const float s = sig[j * 64 + lane];
            float sn, cs;
            sincosf(C * (float)phase, &sn, &cs);
            re += s * cs; im += s * sn;
            phase = (phase + step) & 8191;
        }
    }
    re = wave_red(re); im = wave_red(im);
    __shared__ float mg[4];
    if (lane == 0) mg[wave] = (k <= 4096) ? sqrtf(re * re + im * im) : 0.f;
    __syncthreads();
    if (threadIdx.x == 0)
        atomicAdd(&msc[18 + blockIdx.y], mg[0] + mg[1] + mg[2] + mg[3]);
}

// --- finalize 11 scalar outputs -------------------------------------------
__global__ void finalize(const float* __restrict__ msc,
                         float* __restrict__ out) {
    if (threadIdx.x == 0 && blockIdx.x == 0) {
        const float Nf = 8192.0f;
        const float Sdq = 0.5f * (Nf * msc[5] + msc[10]*msc[10] + msc[11]*msc[11]);
        const float Sqt = 0.5f * (Nf * msc[6] + msc[12]*msc[12] + msc[13]*msc[13]);
        const float Sdv = 0.5f * (Nf * msc[8] + msc[14]*msc[14] + msc[15]*msc[15]);
        const float Svt = 0.5f * (Nf * msc[9] + msc[16]*msc[16] + msc[17]*msc[17]);
        out[8192 + 0]  = sqrtf(msc[3]);
        out[8192 + 1]  = msc[4] / Nf;
        out[8192 + 2]  = msc[5] / (msc[6] + EPSF);
        out[8192 + 3]  = msc[7] / Nf;
        out[8192 + 4]  = msc[8] / (msc[9] + EPSF);
        out[8192 + 5]  = msc[5] / Nf;
        out[8192 + 6]  = msc[8] / Nf;
        out[8192 + 7]  = msc[19] / 4097.0f;
        out[8192 + 8]  = Sdq / (Sqt + EPSF);
        out[8192 + 9]  = msc[18] / 4097.0f;
        out[8192 + 10] = Sdv / (Svt + EPSF);
    }
}

// ---------------------------------------------------------------------------
extern "C" void kernel_launch(void* const* d_in, const int* in_sizes, int n_in,
                              void* d_out, int out_size, void* d_ws, size_t ws_size,
                              hipStream_t stream) {
    const float* x  = (const float*)d_in[1];
    const float* H  = (const float*)d_in[2];
    const float* vt = (const float*)d_in[3];
    const float* qt = (const float*)d_in[4];

    const size_t HH_BYTES  = (size_t)NN * NN * 2;   // 134,217,728 (fp16 H)
    const size_t VEC_BYTES = 80000ull * 4;

    int nb = 512;                                    // row-blocks in fused pass
    const bool fp16ok =
        ws_size >= HH_BYTES + (size_t)512 * NN * 4 + VEC_BYTES;

    ushort_t* Hh = (ushort_t*)d_ws;
    float* spart;
    float* vecs;
    if (fp16ok) {
        spart = (float*)((char*)d_ws + HH_BYTES);
        vecs  = spart + (size_t)512 * NN;
    } else {
        // fp32-direct fallback: only spart + vectors in ws
        while (nb > 64 && ws_size < (size_t)nb * NN * 4 + VEC_BYTES) nb >>= 1;
        spart = (float*)d_ws;
        vecs  = spart + (size_t)nb * NN;
    }
    const int rpb = NN / nb;

    float* v   = vecs;
    float* r   = vecs + 8192;
    float* pA  = vecs + 16384;
    float* pB  = vecs + 24576;
    float* t   = vecs + 32768;
    float* qh  = vecs + 40960;
    float* dv  = vecs + 49152;
    float* dq  = vecs + 57344;
    float* sc  = vecs + 65536;
    float* msc = sc + 80;
    float* out = (float*)d_out;
    float* pbuf[2] = { pA, pB };

    prep<<<32, 256, 0, stream>>>(v, qh, sc);

    // init: b = H^T x  ->  r = b, RS[0] = b.b   (+ fp16 convert when fp16ok)
    if (fp16ok)
        fused_pass<0, 1><<<nb, 512, 0, stream>>>(H, Hh, r, r, x, sc,
                                                 0, 0, 1, 0, rpb,
                                                 t, &sc[79], pA, spart);
    else
        fused_pass<0, 0><<<nb, 512, 0, stream>>>(H, nullptr, r, r, x, sc,
                                                 0, 0, 1, 0, rpb,
                                                 t, &sc[79], pA, spart);
    reduce_update<<<32, 1024, 0, stream>>>(spart, nb, t, pA, r, v, qh, sc,
                                           0, 0, &sc[0], 0);

    for (int it = 0; it < NITER; ++it) {
        const float* pread = (it == 0) ? r : pbuf[(it - 1) & 1];
        float* pwrite = pbuf[it & 1];
        if (fp16ok)
            fused_pass<1, 0><<<nb, 512, 0, stream>>>(Hh, nullptr, r, pread, x,
                                                     sc, it, it - 1,
                                                     (it == 0) ? 1 : 0, 1, rpb,
                                                     t, &sc[40 + it],
                                                     pwrite, spart);
        else
            fused_pass<0, 0><<<nb, 512, 0, stream>>>(H, nullptr, r, pread, x,
                                                     sc, it, it - 1,
                                                     (it == 0) ? 1 : 0, 1, rpb,
                                                     t, &sc[40 + it],
                                                     pwrite, spart);
        reduce_update<<<32, 1024, 0, stream>>>(spart, nb, t, pwrite, r, v, qh,
                                               sc, it, 40 + it, &sc[it + 1], 1);
    }

    metrics1<<<32, 256, 0, stream>>>(qh, v, x, vt, qt, dv, dq, msc, out);
    dim3 g(1025, 2);
    dftmag<<<g, 256, 0, stream>>>(dv, dq, msc);
    finalize<<<1, 64, 0, stream>>>(sc + 80, out);
}

// Round 4
// 1749.690 us; speedup vs baseline: 1.3374x; 1.0012x over previous
//
#include <hip/hip_runtime.h>
#include <hip/hip_fp16.h>
#include <math.h>

// ---------------------------------------------------------------------------
// CGNR solver: v = argmin ||H v - x|| via CG on (H^T H) v = H^T x, 32 iters,
// then reconstruction + time/frequency metrics.  N = 8192.
//
// Round 9: relaxed per-step barrier.  Round-8 ran fused_pass at ~55% of BW:
// __syncthreads() lowers to s_waitcnt vmcnt(0) lgkmcnt(0) + s_barrier, which
// drains the next-pair prefetch loads at EVERY step -> ~900 cy HBM latency
// exposed per step.  The barrier only needs to order the LDS dot-partials,
// so use: ds_write -> s_waitcnt lgkmcnt(0) (no vmcnt!) -> raw s_barrier ->
// ds_read.  Prefetched global loads now stay in flight across the barrier
// (counted-vmcnt pattern).  Partials packed float4 for 4x ds_read_b128
// broadcast.  H stays register-resident between dot and axpy (read once per
// iteration, 134 MB fp16).
//
// sc[] slots: RS[it]=sc[it] (0..32), TT[it]=sc[40+it], metrics msc=sc+80.
// ---------------------------------------------------------------------------

#define NN 8192
#define NITER 32
#define EPSF 1e-20f

typedef unsigned short ushort_t;

__device__ __forceinline__ float wave_red(float v) {
    #pragma unroll
    for (int off = 32; off; off >>= 1) v += __shfl_xor(v, off, 64);
    return v;
}

__device__ __forceinline__ void wred_atomic(float v, float* addr) {
    v = wave_red(v);
    if ((threadIdx.x & 63) == 0) atomicAdd(addr, v);
}

__device__ __forceinline__ void unpack8(uint4 u, float* f) {
    union { unsigned int i; __half2 h; } c0, c1, c2, c3;
    c0.i = u.x; c1.i = u.y; c2.i = u.z; c3.i = u.w;
    float2 f0 = __half22float2(c0.h);
    float2 f1 = __half22float2(c1.h);
    float2 f2 = __half22float2(c2.h);
    float2 f3 = __half22float2(c3.h);
    f[0] = f0.x; f[1] = f0.y; f[2] = f1.x; f[3] = f1.y;
    f[4] = f2.x; f[5] = f2.y; f[6] = f3.x; f[7] = f3.y;
}

// --- packed row fragment (one thread's 16 columns of one H row) ------------
template <int HM> struct RowT;
template <> struct RowT<1> { uint4 a, b; };          // 16 fp16
template <> struct RowT<0> { float f[16]; };         // 16 fp32

__device__ __forceinline__ void load_row(const void* Hp, int row, int tid,
                                         RowT<1>& c) {
    const uint4* hp = (const uint4*)((const ushort_t*)Hp + (size_t)row * NN)
                    + tid * 2;
    c.a = hp[0]; c.b = hp[1];
}
__device__ __forceinline__ void load_row(const void* Hp, int row, int tid,
                                         RowT<0>& c) {
    const float4* hp = (const float4*)((const float*)Hp + (size_t)row * NN)
                     + tid * 4;
    #pragma unroll
    for (int q = 0; q < 4; ++q) {
        float4 v = hp[q];
        c.f[4*q+0] = v.x; c.f[4*q+1] = v.y; c.f[4*q+2] = v.z; c.f[4*q+3] = v.w;
    }
}
__device__ __forceinline__ void unpack_row(const RowT<1>& c, float* f) {
    unpack8(c.a, f); unpack8(c.b, f + 8);
}
__device__ __forceinline__ void unpack_row(const RowT<0>& c, float* f) {
    #pragma unroll
    for (int k = 0; k < 16; ++k) f[k] = c.f[k];
}

// --- fused normal-equations pass -------------------------------------------
// mode 1:  pn = r + beta*p ; t = H pn ; TT += ||t||^2 ;
//          spart[blk] = sum_{rows of blk} t_i * H[i,:] ; block0 stores pn.
//          H rows stay in REGISTERS between the dot and the axpy; the
//          per-step barrier waits lgkmcnt ONLY (prefetch stays in flight).
// mode 0:  spart[blk] = sum_{rows of blk} x_i * H[i,:]   (b = H^T x init);
//          CONV=1 additionally writes the fp16 copy of H.
// grid nb x 512 thr; thread owns 16 columns; rpb = NN/nb rows/block (even).
template <int HM, int CONV>
__global__ __launch_bounds__(512, 4) void fused_pass(
        const void* __restrict__ Hp,
        ushort_t* __restrict__ Hh_out,
        const float* __restrict__ rr,
        const float* __restrict__ pp,
        const float* __restrict__ x,
        const float* __restrict__ sc,
        int bnum, int bden, int first, int mode, int rpb,
        float* __restrict__ tout,
        float* __restrict__ ttout,
        float* __restrict__ pout,
        float* __restrict__ spart) {
    const int tid  = threadIdx.x;
    const int wave = tid >> 6;
    const int lane = tid & 63;
    __shared__ __align__(16) float prt[2][16];   // [buf][2*wave+{0,1}]

    float sacc[16];
    #pragma unroll
    for (int k = 0; k < 16; ++k) sacc[k] = 0.f;

    const int rbase = blockIdx.x * rpb;

    if (mode == 0) {
        // ---- init: b = H^T x (single sweep; optional fp32->fp16 convert) --
        #pragma unroll 2
        for (int i = 0; i < rpb; ++i) {
            const int row = rbase + i;
            RowT<HM> c;
            load_row(Hp, row, tid, c);
            float f[16];
            unpack_row(c, f);
            if (CONV) {
                uint4 pa, pb;
                __half2 h0 = __floats2half2_rn(f[0],  f[1]);
                __half2 h1 = __floats2half2_rn(f[2],  f[3]);
                __half2 h2 = __floats2half2_rn(f[4],  f[5]);
                __half2 h3 = __floats2half2_rn(f[6],  f[7]);
                __half2 h4 = __floats2half2_rn(f[8],  f[9]);
                __half2 h5 = __floats2half2_rn(f[10], f[11]);
                __half2 h6 = __floats2half2_rn(f[12], f[13]);
                __half2 h7 = __floats2half2_rn(f[14], f[15]);
                pa.x = *(unsigned int*)&h0; pa.y = *(unsigned int*)&h1;
                pa.z = *(unsigned int*)&h2; pa.w = *(unsigned int*)&h3;
                pb.x = *(unsigned int*)&h4; pb.y = *(unsigned int*)&h5;
                pb.z = *(unsigned int*)&h6; pb.w = *(unsigned int*)&h7;
                uint4* dst = (uint4*)(Hh_out + (size_t)row * NN) + tid * 2;
                dst[0] = pa; dst[1] = pb;
            }
            const float xv = x[row];
            #pragma unroll
            for (int k = 0; k < 16; ++k) sacc[k] += xv * f[k];
        }
    } else {
        // ---- CG iteration: pn build, then 2-rows-per-step pipeline --------
        float pn[16];
        const float beta = first ? 0.f : sc[bnum] / (sc[bden] + EPSF);
        {
            const float4* r4 = (const float4*)rr + tid * 4;
            const float4* p4 = (const float4*)pp + tid * 4;
            #pragma unroll
            for (int q = 0; q < 4; ++q) {
                float4 a = r4[q], b = p4[q];
                pn[4*q+0] = a.x + beta * b.x; pn[4*q+1] = a.y + beta * b.y;
                pn[4*q+2] = a.z + beta * b.z; pn[4*q+3] = a.w + beta * b.w;
            }
            if (blockIdx.x == 0) {
                float4* o4 = (float4*)pout + tid * 4;
                #pragma unroll
                for (int q = 0; q < 4; ++q) {
                    float4 w;
                    w.x = pn[4*q+0]; w.y = pn[4*q+1];
                    w.z = pn[4*q+2]; w.w = pn[4*q+3];
                    o4[q] = w;
                }
            }
        }

        const int nstep = rpb >> 1;          // 2 rows per step
        float ttacc = 0.f;
        RowT<HM> c0, c1, n0, n1;
        load_row(Hp, rbase + 0, tid, c0);
        load_row(Hp, rbase + 1, tid, c1);

        for (int k = 0; k < nstep; ++k) {
            if (k + 1 < nstep) {              // prefetch next pair (stays in
                load_row(Hp, rbase + 2 * (k + 1) + 0, tid, n0);   // flight
                load_row(Hp, rbase + 2 * (k + 1) + 1, tid, n1);   // across
            }                                                     // barrier)
            float f0[16], f1[16];
            unpack_row(c0, f0);
            unpack_row(c1, f1);
            float dA = 0.f, dB = 0.f;
            #pragma unroll
            for (int j = 0; j < 16; ++j) { dA += f0[j] * pn[j]; dB += f1[j] * pn[j]; }
            dA = wave_red(dA); dB = wave_red(dB);
            const int kb = k & 1;
            if (lane == 0) { prt[kb][2 * wave] = dA; prt[kb][2 * wave + 1] = dB; }
            // commit the LDS write, then raw barrier: lgkmcnt ONLY — the
            // global prefetch loads must NOT be drained here (that was the
            // round-8 stall: __syncthreads implies vmcnt(0)).
            asm volatile("s_waitcnt lgkmcnt(0)" ::: "memory");
            __builtin_amdgcn_s_barrier();
            const float4* pq = (const float4*)prt[kb];
            float4 q0 = pq[0], q1 = pq[1], q2 = pq[2], q3 = pq[3];
            const float tvA = q0.x + q0.z + q1.x + q1.z
                            + q2.x + q2.z + q3.x + q3.z;
            const float tvB = q0.y + q0.w + q1.y + q1.w
                            + q2.y + q2.w + q3.y + q3.w;
            if (tid == 0) {
                tout[rbase + 2 * k + 0] = tvA;
                tout[rbase + 2 * k + 1] = tvB;
                ttacc += tvA * tvA + tvB * tvB;
            }
            #pragma unroll
            for (int j = 0; j < 16; ++j) sacc[j] += tvA * f0[j] + tvB * f1[j];
            c0 = n0; c1 = n1;                 // register renames
        }
        if (tid == 0) atomicAdd(ttout, ttacc);
    }

    float4* sp = (float4*)(spart + (size_t)blockIdx.x * NN) + tid * 4;
    #pragma unroll
    for (int q = 0; q < 4; ++q) {
        float4 w;
        w.x = sacc[4*q+0]; w.y = sacc[4*q+1];
        w.z = sacc[4*q+2]; w.w = sacc[4*q+3];
        sp[q] = w;
    }
}

// --- combine spart column-wise -> s ; apply CG update ----------------------
// mode 0: r = s, RS += s^2
// mode 1: alpha=RS/TT; v += alpha pn; qh += alpha t; r -= alpha s; RS' += r^2
__global__ __launch_bounds__(1024) void reduce_update(
        const float* __restrict__ spart, int nb,
        const float* __restrict__ t,
        const float* __restrict__ pn,
        float* __restrict__ r,
        float* __restrict__ v,
        float* __restrict__ qh,
        const float* __restrict__ sc,
        int anum, int aden,
        float* __restrict__ rsout,
        int mode) {
    const int col = blockIdx.x * 256 + (threadIdx.x & 255);
    const int bq  = threadIdx.x >> 8;
    float s = 0.f;
    #pragma unroll 8
    for (int b = bq; b < nb; b += 4)
        s += spart[(size_t)b * NN + col];
    __shared__ float red[4][256];
    red[bq][threadIdx.x & 255] = s;
    __syncthreads();
    if (bq == 0) {
        s = red[0][threadIdx.x] + red[1][threadIdx.x]
          + red[2][threadIdx.x] + red[3][threadIdx.x];
        float rn;
        if (mode == 0) {
            rn = s;
        } else {
            const float alpha = sc[anum] / (sc[aden] + EPSF);
            v[col]  += alpha * pn[col];
            qh[col] += alpha * t[col];
            rn = r[col] - alpha * s;
        }
        r[col] = rn;
        wred_atomic(rn * rn, rsout);
    }
}

// --- prep: zero v, qh and scalar slots ------------------------------------
__global__ __launch_bounds__(256) void prep(float* v, float* qh, float* sc) {
    const int i = blockIdx.x * 256 + threadIdx.x;
    v[i] = 0.f; qh[i] = 0.f;
    if (i < 128) sc[i] = 0.f;
}

// --- time-domain metrics + difference signals + v output ------------------
__global__ __launch_bounds__(256) void metrics1(const float* __restrict__ qh,
                                                const float* __restrict__ v,
                                                const float* __restrict__ x,
                                                const float* __restrict__ vt,
                                                const float* __restrict__ qt,
                                                float* __restrict__ dv,
                                                float* __restrict__ dq,
                                                float* msc,
                                                float* __restrict__ out) {
    const int i = blockIdx.x * 256 + threadIdx.x;
    const float qhv = qh[i], vv = v[i];
    const float xv = x[i], vtv = vt[i], qtv = qt[i];
    const float dqi = qhv - qtv, dvi = vv - vtv;
    dq[i] = dqi; dv[i] = dvi;
    out[i] = vv;
    const float sg = (i & 1) ? -1.f : 1.f;
    const float rx = qhv - xv;
    wred_atomic(rx * rx,    &msc[3]);
    wred_atomic(fabsf(dqi), &msc[4]);
    wred_atomic(dqi * dqi,  &msc[5]);
    wred_atomic(qtv * qtv,  &msc[6]);
    wred_atomic(fabsf(dvi), &msc[7]);
    wred_atomic(dvi * dvi,  &msc[8]);
    wred_atomic(vtv * vtv,  &msc[9]);
    wred_atomic(dqi,        &msc[10]);
    wred_atomic(sg * dqi,   &msc[11]);
    wred_atomic(qtv,        &msc[12]);
    wred_atomic(sg * qtv,   &msc[13]);
    wred_atomic(dvi,        &msc[14]);
    wred_atomic(sg * dvi,   &msc[15]);
    wred_atomic(vtv,        &msc[16]);
    wred_atomic(sg * vtv,   &msc[17]);
}

// --- direct rDFT magnitudes: one wave per bin k (0..4096) ------------------
__global__ __launch_bounds__(256) void dftmag(const float* __restrict__ dv,
                                              const float* __restrict__ dq,
                                              float* msc) {
    const int wave = threadIdx.x >> 6;
    const int lane = threadIdx.x & 63;
    const int k = blockIdx.x * 4 + wave;
    const float* sig = blockIdx.y ? dq : dv;
    float re = 0.f, im = 0.f;
    if (k <= 4096) {
        const float C = 2.0f * 3.14159265358979323846f / 8192.0f;
        int phase = (k * lane) & 8191;
        const int step = (k << 6) & 8191;
        for (int j = 0; j < 128; ++j) {
            const float s = sig[j * 64 + lane];
            float sn, cs;
            sincosf(C * (float)phase, &sn, &cs);
            re += s * cs; im += s * sn;
            phase = (phase + step) & 8191;
        }
    }
    re = wave_red(re); im = wave_red(im);
    __shared__ float mg[4];
    if (lane == 0) mg[wave] = (k <= 4096) ? sqrtf(re * re + im * im) : 0.f;
    __syncthreads();
    if (threadIdx.x == 0)
        atomicAdd(&msc[18 + blockIdx.y], mg[0] + mg[1] + mg[2] + mg[3]);
}

// --- finalize 11 scalar outputs -------------------------------------------
__global__ void finalize(const float* __restrict__ msc,
                         float* __restrict__ out) {
    if (threadIdx.x == 0 && blockIdx.x == 0) {
        const float Nf = 8192.0f;
        const float Sdq = 0.5f * (Nf * msc[5] + msc[10]*msc[10] + msc[11]*msc[11]);
        const float Sqt = 0.5f * (Nf * msc[6] + msc[12]*msc[12] + msc[13]*msc[13]);
        const float Sdv = 0.5f * (Nf * msc[8] + msc[14]*msc[14] + msc[15]*msc[15]);
        const float Svt = 0.5f * (Nf * msc[9] + msc[16]*msc[16] + msc[17]*msc[17]);
        out[8192 + 0]  = sqrtf(msc[3]);
        out[8192 + 1]  = msc[4] / Nf;
        out[8192 + 2]  = msc[5] / (msc[6] + EPSF);
        out[8192 + 3]  = msc[7] / Nf;
        out[8192 + 4]  = msc[8] / (msc[9] + EPSF);
        out[8192 + 5]  = msc[5] / Nf;
        out[8192 + 6]  = msc[8] / Nf;
        out[8192 + 7]  = msc[19] / 4097.0f;
        out[8192 + 8]  = Sdq / (Sqt + EPSF);
        out[8192 + 9]  = msc[18] / 4097.0f;
        out[8192 + 10] = Sdv / (Svt + EPSF);
    }
}

// ---------------------------------------------------------------------------
extern "C" void kernel_launch(void* const* d_in, const int* in_sizes, int n_in,
                              void* d_out, int out_size, void* d_ws, size_t ws_size,
                              hipStream_t stream) {
    const float* x  = (const float*)d_in[1];
    const float* H  = (const float*)d_in[2];
    const float* vt = (const float*)d_in[3];
    const float* qt = (const float*)d_in[4];

    const size_t HH_BYTES  = (size_t)NN * NN * 2;   // 134,217,728 (fp16 H)
    const size_t VEC_BYTES = 80000ull * 4;

    int nb = 512;                                    // row-blocks in fused pass
    const bool fp16ok =
        ws_size >= HH_BYTES + (size_t)512 * NN * 4 + VEC_BYTES;

    ushort_t* Hh = (ushort_t*)d_ws;
    float* spart;
    float* vecs;
    if (fp16ok) {
        spart = (float*)((char*)d_ws + HH_BYTES);
        vecs  = spart + (size_t)512 * NN;
    } else {
        // fp32-direct fallback: only spart + vectors in ws
        while (nb > 64 && ws_size < (size_t)nb * NN * 4 + VEC_BYTES) nb >>= 1;
        spart = (float*)d_ws;
        vecs  = spart + (size_t)nb * NN;
    }
    const int rpb = NN / nb;

    float* v   = vecs;
    float* r   = vecs + 8192;
    float* pA  = vecs + 16384;
    float* pB  = vecs + 24576;
    float* t   = vecs + 32768;
    float* qh  = vecs + 40960;
    float* dv  = vecs + 49152;
    float* dq  = vecs + 57344;
    float* sc  = vecs + 65536;
    float* msc = sc + 80;
    float* out = (float*)d_out;
    float* pbuf[2] = { pA, pB };

    prep<<<32, 256, 0, stream>>>(v, qh, sc);

    // init: b = H^T x  ->  r = b, RS[0] = b.b   (+ fp16 convert when fp16ok)
    if (fp16ok)
        fused_pass<0, 1><<<nb, 512, 0, stream>>>(H, Hh, r, r, x, sc,
                                                 0, 0, 1, 0, rpb,
                                                 t, &sc[79], pA, spart);
    else
        fused_pass<0, 0><<<nb, 512, 0, stream>>>(H, nullptr, r, r, x, sc,
                                                 0, 0, 1, 0, rpb,
                                                 t, &sc[79], pA, spart);
    reduce_update<<<32, 1024, 0, stream>>>(spart, nb, t, pA, r, v, qh, sc,
                                           0, 0, &sc[0], 0);

    for (int it = 0; it < NITER; ++it) {
        const float* pread = (it == 0) ? r : pbuf[(it - 1) & 1];
        float* pwrite = pbuf[it & 1];
        if (fp16ok)
            fused_pass<1, 0><<<nb, 512, 0, stream>>>(Hh, nullptr, r, pread, x,
                                                     sc, it, it - 1,
                                                     (it == 0) ? 1 : 0, 1, rpb,
                                                     t, &sc[40 + it],
                                                     pwrite, spart);
        else
            fused_pass<0, 0><<<nb, 512, 0, stream>>>(H, nullptr, r, pread, x,
                                                     sc, it, it - 1,
                                                     (it == 0) ? 1 : 0, 1, rpb,
                                                     t, &sc[40 + it],
                                                     pwrite, spart);
        reduce_update<<<32, 1024, 0, stream>>>(spart, nb, t, pwrite, r, v, qh,
                                               sc, it, 40 + it, &sc[it + 1], 1);
    }

    metrics1<<<32, 256, 0, stream>>>(qh, v, x, vt, qt, dv, dq, msc, out);
    dim3 g(1025, 2);
    dftmag<<<g, 256, 0, stream>>>(dv, dq, msc);
    finalize<<<1, 64, 0, stream>>>(sc + 80, out);
}